// Round 2
// 1132.864 us; speedup vs baseline: 1.0346x; 1.0346x over previous
//
#include <hip/hip_runtime.h>
#include <cstdint>

// ---------------------------------------------------------------------------
// MultiModalClinicalGCN — round 4 (resubmit after infra failure):
// LDS-free mel GEMM (latency-bound fix)
//   m  = relu(mel @ W_mel + b_mel)   [N,128]   <-- MFMA 16x16x32 bf16,
//                                                  direct global->reg frags,
//                                                  no LDS, no barriers
//   x2 = relu([clinical|m] @ W_cat)  [N,128]   fp32 tiled
//   h  = x2 @ W1                     [N,128]   fp32 tiled
//   x3 = relu(gather(h))                       CSR gather
//   y  = x3 @ W2                     [N,4]
//   out= gather(y) + b2              [N,4]
// ---------------------------------------------------------------------------

typedef short short4_t __attribute__((ext_vector_type(4)));
typedef short short8_t __attribute__((ext_vector_type(8)));
typedef float floatx4 __attribute__((ext_vector_type(4)));

__device__ __forceinline__ short f2bf(float f) {
  union { float f; unsigned u; } v;
  v.f = f;
  unsigned r = v.u + 0x7fffu + ((v.u >> 16) & 1u);  // RNE
  return (short)(r >> 16);
}

// ---------------- edge utils / CSR build (unchanged) -----------------------
__device__ __forceinline__ bool detect_i64(const int* __restrict__ ei) {
  int nz = 0;
#pragma unroll
  for (int i = 1; i < 64; i += 2) nz |= ei[i];
  return nz == 0;
}
__device__ __forceinline__ int load_src(const int* __restrict__ ei, int e, bool is64) {
  return is64 ? ei[2 * e] : ei[e];
}
__device__ __forceinline__ int load_dst(const int* __restrict__ ei, int e, int E, bool is64) {
  return is64 ? ei[2 * (E + e)] : ei[E + e];
}

__global__ __launch_bounds__(256) void zero_int_k(int* __restrict__ p, int n) {
  int i = blockIdx.x * 256 + threadIdx.x;
  if (i < n) p[i] = 0;
}

__global__ __launch_bounds__(256) void count_deg_k(const int* __restrict__ ei,
                                                   int* __restrict__ degi, int E) {
  const bool is64 = detect_i64(ei);
  int e = blockIdx.x * 256 + threadIdx.x;
  if (e < E) atomicAdd(&degi[load_dst(ei, e, E, is64)], 1);
}

__global__ __launch_bounds__(256) void dinv_k(const int* __restrict__ degi,
                                              float* __restrict__ dinv, int n) {
  int i = blockIdx.x * 256 + threadIdx.x;
  if (i < n) dinv[i] = rsqrtf((float)degi[i] + 1.0f);  // +1 self-loop
}

__global__ __launch_bounds__(256) void scan_reduce_k(const int* __restrict__ degi,
                                                     int* __restrict__ partial, int n) {
  __shared__ int s[256];
  int t = threadIdx.x;
  int i = blockIdx.x * 256 + t;
  s[t] = (i < n) ? degi[i] : 0;
  __syncthreads();
#pragma unroll
  for (int off = 128; off > 0; off >>= 1) {
    if (t < off) s[t] += s[t + off];
    __syncthreads();
  }
  if (t == 0) partial[blockIdx.x] = s[0];
}

__global__ __launch_bounds__(512) void scan_partials_k(const int* __restrict__ partial,
                                                       int* __restrict__ excl, int B,
                                                       int* __restrict__ rowptr, int n, int E) {
  __shared__ int s[512];
  int t = threadIdx.x;
  int v = (t < B) ? partial[t] : 0;
  s[t] = v;
  __syncthreads();
  for (int off = 1; off < 512; off <<= 1) {
    int x = (t >= off) ? s[t - off] : 0;
    __syncthreads();
    s[t] += x;
    __syncthreads();
  }
  if (t < B) excl[t] = s[t] - v;
  if (t == 0) rowptr[n] = E;
}

__global__ __launch_bounds__(256) void scan_final_k(const int* __restrict__ degi,
                                                    const int* __restrict__ excl,
                                                    int* __restrict__ rowptr, int n) {
  __shared__ int s[256];
  int t = threadIdx.x;
  int i = blockIdx.x * 256 + t;
  int v = (i < n) ? degi[i] : 0;
  s[t] = v;
  __syncthreads();
  for (int off = 1; off < 256; off <<= 1) {
    int x = (t >= off) ? s[t - off] : 0;
    __syncthreads();
    s[t] += x;
    __syncthreads();
  }
  if (i < n) rowptr[i] = excl[blockIdx.x] + s[t] - v;
}

__global__ __launch_bounds__(256) void fill_col_k(const int* __restrict__ ei,
                                                  const int* __restrict__ rowptr,
                                                  int* __restrict__ fill,
                                                  int* __restrict__ col, int E) {
  const bool is64 = detect_i64(ei);
  int e = blockIdx.x * 256 + threadIdx.x;
  if (e < E) {
    int s = load_src(ei, e, is64);
    int d = load_dst(ei, e, E, is64);
    int pos = rowptr[d] + atomicAdd(&fill[d], 1);
    col[pos] = s;
  }
}

// --------------- W_mel [1024,128] fp32 -> Wt [128,1024] bf16 ---------------
__global__ __launch_bounds__(256) void convW_k(const float* __restrict__ W,
                                               short* __restrict__ Wt) {
  int idx = blockIdx.x * 256 + threadIdx.x;  // 131072
  int nn = idx >> 10;                        // 0..127
  int k = idx & 1023;                        // 0..1023
  Wt[idx] = f2bf(W[(size_t)k * 128 + nn]);
}

// ---------------------------------------------------------------------------
// MFMA bf16 GEMM, LDS-free: C[n,128] = relu(A[n,1024] @ W + bias)
// Block = 256 thr (4 waves), tile 128 rows. Wave w owns rows w*32..w*32+31
// (2 row-tiles x 8 col-tiles of 16x16x32).
//
// Why no LDS: each wave's A rows are wave-exclusive (no cross-wave reuse),
// and the 16x16x32 A-fragment for lane (cbase,quad) is A[row][k0+quad*8 .. +8]
// — 8 CONTIGUOUS floats. 4 lanes (quad=0..3) of one row cover a full 128B
// line -> direct global loads are perfectly coalesced. B-frags are 16B
// contiguous in pre-transposed Wt (256KB, L2-resident; ~800MB total L2
// traffic ≈ 23us — cheap). Removing the 2-barriers-per-K-chunk staging
// eliminates the vmcnt(0)-drain stall that left MfmaUtil at 3.9%.
// ---------------------------------------------------------------------------
__global__ __launch_bounds__(256) void mel_gemm_mfma_k(const float* __restrict__ A,
                                                       const short* __restrict__ Wt,
                                                       const float* __restrict__ bias,
                                                       float* __restrict__ C, int n) {
  const int tid = threadIdx.x;
  const int lane = tid & 63;
  const int wv = tid >> 6;
  const int quad = lane >> 4;
  const int cbase = lane & 15;
  const int row0 = blockIdx.x * 128;

  // clamp A row pointers for the (store-guarded) tail block
  int r0 = row0 + wv * 32 + cbase;       // tr=0 fragment row
  int r1 = r0 + 16;                      // tr=1 fragment row
  if (r0 > n - 1) r0 = n - 1;
  if (r1 > n - 1) r1 = n - 1;
  const float* __restrict__ a0p = A + (size_t)r0 * 1024;
  const float* __restrict__ a1p = A + (size_t)r1 * 1024;
  const short* __restrict__ bp = Wt + (size_t)cbase * 1024;  // + tc*16*1024 + k

  floatx4 acc[2][8];
#pragma unroll
  for (int tr = 0; tr < 2; ++tr)
#pragma unroll
    for (int tc = 0; tc < 8; ++tc) acc[tr][tc] = (floatx4){0.f, 0.f, 0.f, 0.f};

  for (int kc = 0; kc < 16; ++kc) {  // K = 1024, 64 per iter
#pragma unroll
    for (int kk = 0; kk < 2; ++kk) {
      const int kb = kc * 64 + kk * 32 + quad * 8;
      // A fragments: 2 x float4 per row-tile, contiguous
      floatx4 va00 = *(const floatx4*)(a0p + kb);
      floatx4 va01 = *(const floatx4*)(a0p + kb + 4);
      floatx4 va10 = *(const floatx4*)(a1p + kb);
      floatx4 va11 = *(const floatx4*)(a1p + kb + 4);
      short8_t af0, af1;
#pragma unroll
      for (int j = 0; j < 4; ++j) {
        af0[j] = f2bf(va00[j]);
        af0[j + 4] = f2bf(va01[j]);
        af1[j] = f2bf(va10[j]);
        af1[j + 4] = f2bf(va11[j]);
      }
      // B fragments straight from L2-resident Wt; 16B contiguous per lane
#pragma unroll
      for (int tc = 0; tc < 8; ++tc) {
        short8_t bf = *(const short8_t*)(bp + (size_t)tc * 16384 + kb);
        acc[0][tc] = __builtin_amdgcn_mfma_f32_16x16x32_bf16(af0, bf, acc[0][tc], 0, 0, 0);
        acc[1][tc] = __builtin_amdgcn_mfma_f32_16x16x32_bf16(af1, bf, acc[1][tc], 0, 0, 0);
      }
    }
  }

  // epilogue: C[row][col], col = tc*16+cbase, row = row0+wv*32+tr*16+quad*4+r
  float bb[8];
#pragma unroll
  for (int tc = 0; tc < 8; ++tc) bb[tc] = bias[tc * 16 + cbase];
#pragma unroll
  for (int tr = 0; tr < 2; ++tr) {
#pragma unroll
    for (int r = 0; r < 4; ++r) {
      int grow = row0 + wv * 32 + tr * 16 + quad * 4 + r;
      if (grow < n) {
#pragma unroll
        for (int tc = 0; tc < 8; ++tc) {
          float v = acc[tr][tc][r] + bb[tc];
          C[(size_t)grow * 128 + tc * 16 + cbase] = fmaxf(v, 0.f);
        }
      }
    }
  }
}

// ---------------------------------------------------------------------------
// fp32 tiled GEMM (used for K=128 h = x2@W1)
// ---------------------------------------------------------------------------
template <bool RELU, bool HASBIAS>
__global__ __launch_bounds__(256) void gemm128_k(const float* __restrict__ A, int K,
                                                 const float* __restrict__ B,
                                                 const float* __restrict__ bias,
                                                 float* __restrict__ C, int n) {
  __shared__ float As[64][33];
  __shared__ float4 Bs[32][32];
  const int tid = threadIdx.x;
  const int tx = tid & 31, ty = tid >> 5;
  const int row0 = blockIdx.x * 64;
  float acc[8][4];
#pragma unroll
  for (int i = 0; i < 8; ++i)
#pragma unroll
    for (int j = 0; j < 4; ++j) acc[i][j] = 0.f;

  const int nChunks = K >> 5;
  for (int kc = 0; kc < nChunks; ++kc) {
    __syncthreads();
#pragma unroll
    for (int j = 0; j < 2; ++j) {
      int idx = tid + j * 256;
      int ar = idx >> 3, ac4 = idx & 7;
      int grow = row0 + ar;
      float4 v = make_float4(0.f, 0.f, 0.f, 0.f);
      if (grow < n) v = *(const float4*)(A + (size_t)grow * K + kc * 32 + ac4 * 4);
      As[ar][ac4 * 4 + 0] = v.x;
      As[ar][ac4 * 4 + 1] = v.y;
      As[ar][ac4 * 4 + 2] = v.z;
      As[ar][ac4 * 4 + 3] = v.w;
    }
#pragma unroll
    for (int j = 0; j < 4; ++j) {
      int idx = tid + j * 256;
      int br = idx >> 5, bc4 = idx & 31;
      Bs[br][bc4] = *(const float4*)(B + (size_t)(kc * 32 + br) * 128 + bc4 * 4);
    }
    __syncthreads();
#pragma unroll
    for (int kk = 0; kk < 32; ++kk) {
      float4 b = Bs[kk][tx];
#pragma unroll
      for (int i = 0; i < 8; ++i) {
        float a = As[ty * 8 + i][kk];
        acc[i][0] += a * b.x;
        acc[i][1] += a * b.y;
        acc[i][2] += a * b.z;
        acc[i][3] += a * b.w;
      }
    }
  }
  float4 bb = make_float4(0.f, 0.f, 0.f, 0.f);
  if (HASBIAS) bb = *(const float4*)(bias + tx * 4);
#pragma unroll
  for (int i = 0; i < 8; ++i) {
    int grow = row0 + ty * 8 + i;
    if (grow < n) {
      float4 o;
      o.x = acc[i][0] + bb.x;
      o.y = acc[i][1] + bb.y;
      o.z = acc[i][2] + bb.z;
      o.w = acc[i][3] + bb.w;
      if (RELU) {
        o.x = fmaxf(o.x, 0.f);
        o.y = fmaxf(o.y, 0.f);
        o.z = fmaxf(o.z, 0.f);
        o.w = fmaxf(o.w, 0.f);
      }
      *(float4*)(C + (size_t)grow * 128 + tx * 4) = o;
    }
  }
}

// A = [clinical(64) | m(128)] fused (K = 192), relu + bias.
__global__ __launch_bounds__(256) void gemm_cat_k(const float* __restrict__ A1,
                                                  const float* __restrict__ A2,
                                                  const float* __restrict__ B,
                                                  const float* __restrict__ bias,
                                                  float* __restrict__ C, int n) {
  __shared__ float As[64][33];
  __shared__ float4 Bs[32][32];
  const int tid = threadIdx.x;
  const int tx = tid & 31, ty = tid >> 5;
  const int row0 = blockIdx.x * 64;
  float acc[8][4];
#pragma unroll
  for (int i = 0; i < 8; ++i)
#pragma unroll
    for (int j = 0; j < 4; ++j) acc[i][j] = 0.f;

  for (int kc = 0; kc < 6; ++kc) {
    __syncthreads();
#pragma unroll
    for (int j = 0; j < 2; ++j) {
      int idx = tid + j * 256;
      int ar = idx >> 3, ac4 = idx & 7;
      int grow = row0 + ar;
      int kcol = kc * 32 + ac4 * 4;
      float4 v = make_float4(0.f, 0.f, 0.f, 0.f);
      if (grow < n) {
        v = (kcol < 64) ? *(const float4*)(A1 + (size_t)grow * 64 + kcol)
                        : *(const float4*)(A2 + (size_t)grow * 128 + (kcol - 64));
      }
      As[ar][ac4 * 4 + 0] = v.x;
      As[ar][ac4 * 4 + 1] = v.y;
      As[ar][ac4 * 4 + 2] = v.z;
      As[ar][ac4 * 4 + 3] = v.w;
    }
#pragma unroll
    for (int j = 0; j < 4; ++j) {
      int idx = tid + j * 256;
      int br = idx >> 5, bc4 = idx & 31;
      Bs[br][bc4] = *(const float4*)(B + (size_t)(kc * 32 + br) * 128 + bc4 * 4);
    }
    __syncthreads();
#pragma unroll
    for (int kk = 0; kk < 32; ++kk) {
      float4 b = Bs[kk][tx];
#pragma unroll
      for (int i = 0; i < 8; ++i) {
        float a = As[ty * 8 + i][kk];
        acc[i][0] += a * b.x;
        acc[i][1] += a * b.y;
        acc[i][2] += a * b.z;
        acc[i][3] += a * b.w;
      }
    }
  }
  float4 bb = *(const float4*)(bias + tx * 4);
#pragma unroll
  for (int i = 0; i < 8; ++i) {
    int grow = row0 + ty * 8 + i;
    if (grow < n) {
      float4 o;
      o.x = fmaxf(acc[i][0] + bb.x, 0.f);
      o.y = fmaxf(acc[i][1] + bb.y, 0.f);
      o.z = fmaxf(acc[i][2] + bb.z, 0.f);
      o.w = fmaxf(acc[i][3] + bb.w, 0.f);
      *(float4*)(C + (size_t)grow * 128 + tx * 4) = o;
    }
  }
}

// ---------------------------------------------------------------------------
// Gather-form propagate, 128 feats: 128 threads per node (block = 2 nodes).
// ---------------------------------------------------------------------------
template <bool RELU>
__global__ __launch_bounds__(256) void gather128_k(const int* __restrict__ col,
                                                   const int* __restrict__ rowptr,
                                                   const float* __restrict__ dinv,
                                                   const float* __restrict__ h,
                                                   const float* __restrict__ bias,
                                                   float* __restrict__ out, int n) {
  const int node = blockIdx.x * 2 + (threadIdx.x >> 7);
  const int f = threadIdx.x & 127;
  if (node >= n) return;
  const int beg = rowptr[node], end = rowptr[node + 1];
  float acc = 0.f;
  int p = beg;
  for (; p + 4 <= end; p += 4) {
    int s0 = col[p], s1 = col[p + 1], s2 = col[p + 2], s3 = col[p + 3];
    float d0 = dinv[s0], d1 = dinv[s1], d2 = dinv[s2], d3 = dinv[s3];
    float h0 = h[(size_t)s0 * 128 + f];
    float h1 = h[(size_t)s1 * 128 + f];
    float h2 = h[(size_t)s2 * 128 + f];
    float h3 = h[(size_t)s3 * 128 + f];
    acc += d0 * h0 + d1 * h1 + d2 * h2 + d3 * h3;
  }
  for (; p < end; ++p) {
    int s = col[p];
    acc += dinv[s] * h[(size_t)s * 128 + f];
  }
  const float di = dinv[node];
  float v = di * (acc + di * h[(size_t)node * 128 + f]) + bias[f];
  if (RELU) v = fmaxf(v, 0.f);
  out[(size_t)node * 128 + f] = v;
}

// y[n,4] = A[n,128] @ W[128,4]
__global__ __launch_bounds__(256) void gemm_small4_k(const float* __restrict__ A,
                                                     const float* __restrict__ W,
                                                     float* __restrict__ Y, int n) {
  __shared__ float Ws[512];
  int tid = threadIdx.x;
  Ws[tid] = W[tid];
  Ws[tid + 256] = W[tid + 256];
  __syncthreads();
  int row = blockIdx.x * 256 + tid;
  if (row >= n) return;
  const float4* A4 = (const float4*)(A + (size_t)row * 128);
  float a0 = 0.f, a1 = 0.f, a2 = 0.f, a3 = 0.f;
#pragma unroll
  for (int k4 = 0; k4 < 32; ++k4) {
    float4 a = A4[k4];
    const float* w = &Ws[k4 * 16];
    a0 += a.x * w[0] + a.y * w[4] + a.z * w[8] + a.w * w[12];
    a1 += a.x * w[1] + a.y * w[5] + a.z * w[9] + a.w * w[13];
    a2 += a.x * w[2] + a.y * w[6] + a.z * w[10] + a.w * w[14];
    a3 += a.x * w[3] + a.y * w[7] + a.z * w[11] + a.w * w[15];
  }
  *(float4*)(Y + (size_t)row * 4) = make_float4(a0, a1, a2, a3);
}

// Gather-form propagate, 4 feats: 1 thread per node.
__global__ __launch_bounds__(256) void gather4_k(const int* __restrict__ col,
                                                 const int* __restrict__ rowptr,
                                                 const float* __restrict__ dinv,
                                                 const float* __restrict__ y,
                                                 const float* __restrict__ b2,
                                                 float* __restrict__ out, int n) {
  int node = blockIdx.x * 256 + threadIdx.x;
  if (node >= n) return;
  const int beg = rowptr[node], end = rowptr[node + 1];
  float ax = 0.f, ay = 0.f, az = 0.f, aw = 0.f;
  int p = beg;
  for (; p + 2 <= end; p += 2) {
    int s0 = col[p], s1 = col[p + 1];
    float d0 = dinv[s0], d1 = dinv[s1];
    float4 y0 = *(const float4*)(y + (size_t)s0 * 4);
    float4 y1 = *(const float4*)(y + (size_t)s1 * 4);
    ax += d0 * y0.x + d1 * y1.x;
    ay += d0 * y0.y + d1 * y1.y;
    az += d0 * y0.z + d1 * y1.z;
    aw += d0 * y0.w + d1 * y1.w;
  }
  for (; p < end; ++p) {
    int s = col[p];
    float ds = dinv[s];
    float4 yv = *(const float4*)(y + (size_t)s * 4);
    ax += ds * yv.x;
    ay += ds * yv.y;
    az += ds * yv.z;
    aw += ds * yv.w;
  }
  const float di = dinv[node];
  float4 yd = *(const float4*)(y + (size_t)node * 4);
  float4 o;
  o.x = di * (ax + di * yd.x) + b2[0];
  o.y = di * (ay + di * yd.y) + b2[1];
  o.z = di * (az + di * yd.z) + b2[2];
  o.w = di * (aw + di * yd.w) + b2[3];
  *(float4*)(out + (size_t)node * 4) = o;
}

extern "C" void kernel_launch(void* const* d_in, const int* in_sizes, int n_in,
                              void* d_out, int out_size, void* d_ws, size_t ws_size,
                              hipStream_t stream) {
  const float* clinical = (const float*)d_in[0];
  const float* mel = (const float*)d_in[1];
  const int* ei = (const int*)d_in[2];
  const float* W_mel = (const float*)d_in[3];
  const float* b_mel = (const float*)d_in[4];
  const float* W_cat = (const float*)d_in[5];
  const float* b_cat = (const float*)d_in[6];
  const float* W1 = (const float*)d_in[7];
  const float* b1 = (const float*)d_in[8];
  const float* W2 = (const float*)d_in[9];
  const float* b2 = (const float*)d_in[10];
  float* out = (float*)d_out;

  const int N = in_sizes[0] / 64;   // 100000
  const int E = in_sizes[2] / 2;    // 1600000
  const int B = (N + 255) / 256;    // scan blocks (391)

  // Workspace layout:
  //   bufA [N*128] f | bufB [N*128] f | dinv [N] f | ybuf [N*4] f |
  //   degi [N] i | rowptr [N+1] i | fill [N] i | partial [512] i |
  //   excl [512] i | col [E] i | Wt [1024*128] short
  float* bufA = (float*)d_ws;
  float* bufB = bufA + (size_t)N * 128;
  float* dinv = bufB + (size_t)N * 128;
  float* ybuf = dinv + N;
  int* degi = (int*)(ybuf + (size_t)N * 4);
  int* rowptr = degi + N;
  int* fill = rowptr + (N + 1);
  int* partial = fill + N;
  int* excl = partial + 512;
  int* col = excl + 512;
  short* Wt = (short*)(col + E);

  const dim3 blk(256);

  // ---- CSR build + dinv + weight conversion
  zero_int_k<<<(N + 255) / 256, blk, 0, stream>>>(degi, N);
  count_deg_k<<<(E + 255) / 256, blk, 0, stream>>>(ei, degi, E);
  dinv_k<<<B, blk, 0, stream>>>(degi, dinv, N);
  scan_reduce_k<<<B, blk, 0, stream>>>(degi, partial, N);
  scan_partials_k<<<1, 512, 0, stream>>>(partial, excl, B, rowptr, N, E);
  scan_final_k<<<B, blk, 0, stream>>>(degi, excl, rowptr, N);
  zero_int_k<<<B, blk, 0, stream>>>(fill, N);
  fill_col_k<<<(E + 255) / 256, blk, 0, stream>>>(ei, rowptr, fill, col, E);
  convW_k<<<512, blk, 0, stream>>>(W_mel, Wt);

  // ---- dense pipeline
  mel_gemm_mfma_k<<<(N + 127) / 128, blk, 0, stream>>>(mel, Wt, b_mel, bufA, N);
  gemm_cat_k<<<(N + 63) / 64, blk, 0, stream>>>(clinical, bufA, W_cat, b_cat, bufB, N);
  gemm128_k<false, false><<<(N + 63) / 64, blk, 0, stream>>>(bufB, 128, W1, nullptr, bufA, N);

  // ---- propagate 1 (fused finish+relu), bufA(h) -> bufB(x3)
  gather128_k<true><<<(N + 1) / 2, blk, 0, stream>>>(col, rowptr, dinv, bufA, b1, bufB, N);

  // ---- y = x3 @ W2 -> ybuf
  gemm_small4_k<<<(N + 255) / 256, blk, 0, stream>>>(bufB, W2, ybuf, N);

  // ---- propagate 2 (fused finish), ybuf -> out
  gather4_k<<<(N + 255) / 256, blk, 0, stream>>>(col, rowptr, dinv, ybuf, b2, out, N);
}

// Round 3
// 1098.876 us; speedup vs baseline: 1.0666x; 1.0309x over previous
//
#include <hip/hip_runtime.h>
#include <cstdint>

// ---------------------------------------------------------------------------
// MultiModalClinicalGCN — round 5: fuse cat+W1 GEMMs into one barrier-free
// MFMA kernel with bf16x3 precision split.
//   m  = relu(mel @ W_mel + b_mel)   [N,128]   MFMA bf16, LDS-free
//   h  = relu([clin|m]@Wcat+bcat)@W1 [N,128]   MFMA bf16x3 split, fused,
//                                              wave-private LDS transpose,
//                                              ZERO barriers
//   x3 = relu(gather(h))                       CSR gather
//   y  = x3 @ W2                     [N,4]
//   out= gather(y) + b2              [N,4]
// ---------------------------------------------------------------------------

typedef short short4_t __attribute__((ext_vector_type(4)));
typedef short short8_t __attribute__((ext_vector_type(8)));
typedef float floatx4 __attribute__((ext_vector_type(4)));

__device__ __forceinline__ short f2bf(float f) {
  union { float f; unsigned u; } v;
  v.f = f;
  unsigned r = v.u + 0x7fffu + ((v.u >> 16) & 1u);  // RNE
  return (short)(r >> 16);
}
__device__ __forceinline__ float bf2f(short h) {
  union { unsigned u; float f; } v;
  v.u = ((unsigned)(unsigned short)h) << 16;
  return v.f;
}

// ---------------- edge utils / CSR build (unchanged) -----------------------
__device__ __forceinline__ bool detect_i64(const int* __restrict__ ei) {
  int nz = 0;
#pragma unroll
  for (int i = 1; i < 64; i += 2) nz |= ei[i];
  return nz == 0;
}
__device__ __forceinline__ int load_src(const int* __restrict__ ei, int e, bool is64) {
  return is64 ? ei[2 * e] : ei[e];
}
__device__ __forceinline__ int load_dst(const int* __restrict__ ei, int e, int E, bool is64) {
  return is64 ? ei[2 * (E + e)] : ei[E + e];
}

__global__ __launch_bounds__(256) void zero_int_k(int* __restrict__ p, int n) {
  int i = blockIdx.x * 256 + threadIdx.x;
  if (i < n) p[i] = 0;
}

__global__ __launch_bounds__(256) void count_deg_k(const int* __restrict__ ei,
                                                   int* __restrict__ degi, int E) {
  const bool is64 = detect_i64(ei);
  int e = blockIdx.x * 256 + threadIdx.x;
  if (e < E) atomicAdd(&degi[load_dst(ei, e, E, is64)], 1);
}

__global__ __launch_bounds__(256) void dinv_k(const int* __restrict__ degi,
                                              float* __restrict__ dinv, int n) {
  int i = blockIdx.x * 256 + threadIdx.x;
  if (i < n) dinv[i] = rsqrtf((float)degi[i] + 1.0f);  // +1 self-loop
}

__global__ __launch_bounds__(256) void scan_reduce_k(const int* __restrict__ degi,
                                                     int* __restrict__ partial, int n) {
  __shared__ int s[256];
  int t = threadIdx.x;
  int i = blockIdx.x * 256 + t;
  s[t] = (i < n) ? degi[i] : 0;
  __syncthreads();
#pragma unroll
  for (int off = 128; off > 0; off >>= 1) {
    if (t < off) s[t] += s[t + off];
    __syncthreads();
  }
  if (t == 0) partial[blockIdx.x] = s[0];
}

__global__ __launch_bounds__(512) void scan_partials_k(const int* __restrict__ partial,
                                                       int* __restrict__ excl, int B,
                                                       int* __restrict__ rowptr, int n, int E) {
  __shared__ int s[512];
  int t = threadIdx.x;
  int v = (t < B) ? partial[t] : 0;
  s[t] = v;
  __syncthreads();
  for (int off = 1; off < 512; off <<= 1) {
    int x = (t >= off) ? s[t - off] : 0;
    __syncthreads();
    s[t] += x;
    __syncthreads();
  }
  if (t < B) excl[t] = s[t] - v;
  if (t == 0) rowptr[n] = E;
}

__global__ __launch_bounds__(256) void scan_final_k(const int* __restrict__ degi,
                                                    const int* __restrict__ excl,
                                                    int* __restrict__ rowptr, int n) {
  __shared__ int s[256];
  int t = threadIdx.x;
  int i = blockIdx.x * 256 + t;
  int v = (i < n) ? degi[i] : 0;
  s[t] = v;
  __syncthreads();
  for (int off = 1; off < 256; off <<= 1) {
    int x = (t >= off) ? s[t - off] : 0;
    __syncthreads();
    s[t] += x;
    __syncthreads();
  }
  if (i < n) rowptr[i] = excl[blockIdx.x] + s[t] - v;
}

__global__ __launch_bounds__(256) void fill_col_k(const int* __restrict__ ei,
                                                  const int* __restrict__ rowptr,
                                                  int* __restrict__ fill,
                                                  int* __restrict__ col, int E) {
  const bool is64 = detect_i64(ei);
  int e = blockIdx.x * 256 + threadIdx.x;
  if (e < E) {
    int s = load_src(ei, e, is64);
    int d = load_dst(ei, e, E, is64);
    int pos = rowptr[d] + atomicAdd(&fill[d], 1);
    col[pos] = s;
  }
}

// --------------- W_mel [1024,128] fp32 -> Wt [128,1024] bf16 ---------------
__global__ __launch_bounds__(256) void convW_k(const float* __restrict__ W,
                                               short* __restrict__ Wt) {
  int idx = blockIdx.x * 256 + threadIdx.x;  // 131072
  int nn = idx >> 10;                        // 0..127
  int k = idx & 1023;                        // 0..1023
  Wt[idx] = f2bf(W[(size_t)k * 128 + nn]);
}

// --------------- W [K,C=128] fp32 -> T_hi/T_lo [C][K] bf16 split -----------
// block = K threads (one output column per block): T[c*K + k] = split(W[k*128+c])
__global__ void convWsplit_k(const float* __restrict__ W, short* __restrict__ Thi,
                             short* __restrict__ Tlo, int K) {
  int c = blockIdx.x;        // 0..127
  int k = threadIdx.x;       // 0..K-1
  if (k >= K) return;
  float w = W[(size_t)k * 128 + c];
  short hi = f2bf(w);
  short lo = f2bf(w - bf2f(hi));
  Thi[(size_t)c * K + k] = hi;
  Tlo[(size_t)c * K + k] = lo;
}

// ---------------------------------------------------------------------------
// MFMA bf16 GEMM, LDS-free: C[n,128] = relu(A[n,1024] @ W + bias)
// Block = 256 thr (4 waves), tile 128 rows. Wave w owns rows w*32..w*32+31
// (2 row-tiles x 8 col-tiles of 16x16x32). No LDS, no barriers.
// ---------------------------------------------------------------------------
__global__ __launch_bounds__(256) void mel_gemm_mfma_k(const float* __restrict__ A,
                                                       const short* __restrict__ Wt,
                                                       const float* __restrict__ bias,
                                                       float* __restrict__ C, int n) {
  const int tid = threadIdx.x;
  const int lane = tid & 63;
  const int wv = tid >> 6;
  const int quad = lane >> 4;
  const int cbase = lane & 15;
  const int row0 = blockIdx.x * 128;

  int r0 = row0 + wv * 32 + cbase;       // tr=0 fragment row
  int r1 = r0 + 16;                      // tr=1 fragment row
  if (r0 > n - 1) r0 = n - 1;
  if (r1 > n - 1) r1 = n - 1;
  const float* __restrict__ a0p = A + (size_t)r0 * 1024;
  const float* __restrict__ a1p = A + (size_t)r1 * 1024;
  const short* __restrict__ bp = Wt + (size_t)cbase * 1024;

  floatx4 acc[2][8];
#pragma unroll
  for (int tr = 0; tr < 2; ++tr)
#pragma unroll
    for (int tc = 0; tc < 8; ++tc) acc[tr][tc] = (floatx4){0.f, 0.f, 0.f, 0.f};

  for (int kc = 0; kc < 16; ++kc) {  // K = 1024, 64 per iter
#pragma unroll
    for (int kk = 0; kk < 2; ++kk) {
      const int kb = kc * 64 + kk * 32 + quad * 8;
      floatx4 va00 = *(const floatx4*)(a0p + kb);
      floatx4 va01 = *(const floatx4*)(a0p + kb + 4);
      floatx4 va10 = *(const floatx4*)(a1p + kb);
      floatx4 va11 = *(const floatx4*)(a1p + kb + 4);
      short8_t af0, af1;
#pragma unroll
      for (int j = 0; j < 4; ++j) {
        af0[j] = f2bf(va00[j]);
        af0[j + 4] = f2bf(va01[j]);
        af1[j] = f2bf(va10[j]);
        af1[j + 4] = f2bf(va11[j]);
      }
#pragma unroll
      for (int tc = 0; tc < 8; ++tc) {
        short8_t bf = *(const short8_t*)(bp + (size_t)tc * 16384 + kb);
        acc[0][tc] = __builtin_amdgcn_mfma_f32_16x16x32_bf16(af0, bf, acc[0][tc], 0, 0, 0);
        acc[1][tc] = __builtin_amdgcn_mfma_f32_16x16x32_bf16(af1, bf, acc[1][tc], 0, 0, 0);
      }
    }
  }

  float bb[8];
#pragma unroll
  for (int tc = 0; tc < 8; ++tc) bb[tc] = bias[tc * 16 + cbase];
#pragma unroll
  for (int tr = 0; tr < 2; ++tr) {
#pragma unroll
    for (int r = 0; r < 4; ++r) {
      int grow = row0 + wv * 32 + tr * 16 + quad * 4 + r;
      if (grow < n) {
#pragma unroll
        for (int tc = 0; tc < 8; ++tc) {
          float v = acc[tr][tc][r] + bb[tc];
          C[(size_t)grow * 128 + tc * 16 + cbase] = fmaxf(v, 0.f);
        }
      }
    }
  }
}

// ---------------------------------------------------------------------------
// Fused: H = relu([clin(64)|m(128)] @ Wcat + bcat) @ W1      [n,128]
// MFMA bf16x3 precision split (hi*hi + hi*lo + lo*hi ~= fp32).
// Block = 256 thr (4 waves), 128 rows/block, LDS-free A loads.
// x2 transpose stage is WAVE-PRIVATE (each wave reads exactly the 32 rows it
// wrote) -> zero __syncthreads. LDS XOR-swizzled: idx ^= (row&7)<<3 (shorts),
// so stage-2 ds_read_b128 A-frags are conflict-free (G4).
// In-place H=bufA is safe: block-exclusive row ranges; within a wave all m
// loads are consumed (vmcnt-waited) before any H store issues.
// ---------------------------------------------------------------------------
__global__ __launch_bounds__(256) void cat_w1_mfma_k(
    const float* __restrict__ clin, const float* __restrict__ m,
    const short* __restrict__ WcT_hi, const short* __restrict__ WcT_lo,
    const short* __restrict__ W1T_hi, const short* __restrict__ W1T_lo,
    const float* __restrict__ bcat, float* __restrict__ H, int n) {
  __shared__ short Xhi[4][4096];  // [wave][32 rows x 128 cols], swizzled
  __shared__ short Xlo[4][4096];
  const int tid = threadIdx.x;
  const int lane = tid & 63;
  const int wv = tid >> 6;
  const int quad = lane >> 4;
  const int cbase = lane & 15;
  const int row0 = blockIdx.x * 128;

  int r0 = row0 + wv * 32 + cbase;
  int r1 = r0 + 16;
  if (r0 > n - 1) r0 = n - 1;
  if (r1 > n - 1) r1 = n - 1;
  const float* __restrict__ c0p = clin + (size_t)r0 * 64;
  const float* __restrict__ c1p = clin + (size_t)r1 * 64;
  const float* __restrict__ m0p = m + (size_t)r0 * 128;
  const float* __restrict__ m1p = m + (size_t)r1 * 128;

  floatx4 acc[2][8];
#pragma unroll
  for (int tr = 0; tr < 2; ++tr)
#pragma unroll
    for (int tc = 0; tc < 8; ++tc) acc[tr][tc] = (floatx4){0.f, 0.f, 0.f, 0.f};

  // ---- stage 1: x2 = [clin|m] @ Wcat  (K = 192; kb<64 -> clin, else m)
#pragma unroll
  for (int kb = 0; kb < 192; kb += 32) {
    const int ko = kb + quad * 8;
    floatx4 v0a, v0b, v1a, v1b;
    if (kb < 64) {
      v0a = *(const floatx4*)(c0p + ko);
      v0b = *(const floatx4*)(c0p + ko + 4);
      v1a = *(const floatx4*)(c1p + ko);
      v1b = *(const floatx4*)(c1p + ko + 4);
    } else {
      v0a = *(const floatx4*)(m0p + ko - 64);
      v0b = *(const floatx4*)(m0p + ko - 60);
      v1a = *(const floatx4*)(m1p + ko - 64);
      v1b = *(const floatx4*)(m1p + ko - 60);
    }
    short8_t a0h, a0l, a1h, a1l;
#pragma unroll
    for (int j = 0; j < 4; ++j) {
      a0h[j] = f2bf(v0a[j]);     a0l[j] = f2bf(v0a[j] - bf2f(a0h[j]));
      a0h[j + 4] = f2bf(v0b[j]); a0l[j + 4] = f2bf(v0b[j] - bf2f(a0h[j + 4]));
      a1h[j] = f2bf(v1a[j]);     a1l[j] = f2bf(v1a[j] - bf2f(a1h[j]));
      a1h[j + 4] = f2bf(v1b[j]); a1l[j + 4] = f2bf(v1b[j] - bf2f(a1h[j + 4]));
    }
#pragma unroll
    for (int tc = 0; tc < 8; ++tc) {
      const short* bpp = WcT_hi + (size_t)(tc * 16 + cbase) * 192 + ko;
      const short* bpl = WcT_lo + (size_t)(tc * 16 + cbase) * 192 + ko;
      short8_t bh = *(const short8_t*)bpp;
      short8_t bl = *(const short8_t*)bpl;
      acc[0][tc] = __builtin_amdgcn_mfma_f32_16x16x32_bf16(a0h, bh, acc[0][tc], 0, 0, 0);
      acc[0][tc] = __builtin_amdgcn_mfma_f32_16x16x32_bf16(a0h, bl, acc[0][tc], 0, 0, 0);
      acc[0][tc] = __builtin_amdgcn_mfma_f32_16x16x32_bf16(a0l, bh, acc[0][tc], 0, 0, 0);
      acc[1][tc] = __builtin_amdgcn_mfma_f32_16x16x32_bf16(a1h, bh, acc[1][tc], 0, 0, 0);
      acc[1][tc] = __builtin_amdgcn_mfma_f32_16x16x32_bf16(a1h, bl, acc[1][tc], 0, 0, 0);
      acc[1][tc] = __builtin_amdgcn_mfma_f32_16x16x32_bf16(a1l, bh, acc[1][tc], 0, 0, 0);
    }
  }

  // ---- epilogue 1: relu+bias, split, wave-private swizzled LDS write
  float bb[8];
#pragma unroll
  for (int tc = 0; tc < 8; ++tc) bb[tc] = bcat[tc * 16 + cbase];
  short* __restrict__ xh = &Xhi[wv][0];
  short* __restrict__ xl = &Xlo[wv][0];
#pragma unroll
  for (int tr = 0; tr < 2; ++tr) {
#pragma unroll
    for (int tc = 0; tc < 8; ++tc) {
      const int col = tc * 16 + cbase;
#pragma unroll
      for (int r = 0; r < 4; ++r) {
        const int lrow = tr * 16 + quad * 4 + r;
        float v = fmaxf(acc[tr][tc][r] + bb[tc], 0.f);
        short hi = f2bf(v);
        short lo = f2bf(v - bf2f(hi));
        const int idx = (lrow * 128 + col) ^ ((lrow & 7) << 3);
        xh[idx] = hi;
        xl[idx] = lo;
      }
    }
  }

  // ---- stage 2: H = x2 @ W1 (K = 128), A-frags from wave-private LDS
  floatx4 acc2[2][8];
#pragma unroll
  for (int tr = 0; tr < 2; ++tr)
#pragma unroll
    for (int tc = 0; tc < 8; ++tc) acc2[tr][tc] = (floatx4){0.f, 0.f, 0.f, 0.f};

#pragma unroll
  for (int kb = 0; kb < 128; kb += 32) {
    const int k = kb + quad * 8;
    short8_t ah[2], al[2];
#pragma unroll
    for (int tr = 0; tr < 2; ++tr) {
      const int lrow = tr * 16 + cbase;
      const int idx = (lrow * 128 + k) ^ ((lrow & 7) << 3);
      ah[tr] = *(const short8_t*)&xh[idx];
      al[tr] = *(const short8_t*)&xl[idx];
    }
#pragma unroll
    for (int tc = 0; tc < 8; ++tc) {
      short8_t bh = *(const short8_t*)(W1T_hi + (size_t)(tc * 16 + cbase) * 128 + k);
      short8_t bl = *(const short8_t*)(W1T_lo + (size_t)(tc * 16 + cbase) * 128 + k);
#pragma unroll
      for (int tr = 0; tr < 2; ++tr) {
        acc2[tr][tc] = __builtin_amdgcn_mfma_f32_16x16x32_bf16(ah[tr], bh, acc2[tr][tc], 0, 0, 0);
        acc2[tr][tc] = __builtin_amdgcn_mfma_f32_16x16x32_bf16(ah[tr], bl, acc2[tr][tc], 0, 0, 0);
        acc2[tr][tc] = __builtin_amdgcn_mfma_f32_16x16x32_bf16(al[tr], bh, acc2[tr][tc], 0, 0, 0);
      }
    }
  }

  // ---- epilogue 2: write H (no bias/relu; b1 is applied in gather128)
#pragma unroll
  for (int tr = 0; tr < 2; ++tr) {
#pragma unroll
    for (int r = 0; r < 4; ++r) {
      int grow = row0 + wv * 32 + tr * 16 + quad * 4 + r;
      if (grow < n) {
#pragma unroll
        for (int tc = 0; tc < 8; ++tc)
          H[(size_t)grow * 128 + tc * 16 + cbase] = acc2[tr][tc][r];
      }
    }
  }
}

// ---------------------------------------------------------------------------
// Gather-form propagate, 128 feats: 128 threads per node (block = 2 nodes).
// ---------------------------------------------------------------------------
template <bool RELU>
__global__ __launch_bounds__(256) void gather128_k(const int* __restrict__ col,
                                                   const int* __restrict__ rowptr,
                                                   const float* __restrict__ dinv,
                                                   const float* __restrict__ h,
                                                   const float* __restrict__ bias,
                                                   float* __restrict__ out, int n) {
  const int node = blockIdx.x * 2 + (threadIdx.x >> 7);
  const int f = threadIdx.x & 127;
  if (node >= n) return;
  const int beg = rowptr[node], end = rowptr[node + 1];
  float acc = 0.f;
  int p = beg;
  for (; p + 4 <= end; p += 4) {
    int s0 = col[p], s1 = col[p + 1], s2 = col[p + 2], s3 = col[p + 3];
    float d0 = dinv[s0], d1 = dinv[s1], d2 = dinv[s2], d3 = dinv[s3];
    float h0 = h[(size_t)s0 * 128 + f];
    float h1 = h[(size_t)s1 * 128 + f];
    float h2 = h[(size_t)s2 * 128 + f];
    float h3 = h[(size_t)s3 * 128 + f];
    acc += d0 * h0 + d1 * h1 + d2 * h2 + d3 * h3;
  }
  for (; p < end; ++p) {
    int s = col[p];
    acc += dinv[s] * h[(size_t)s * 128 + f];
  }
  const float di = dinv[node];
  float v = di * (acc + di * h[(size_t)node * 128 + f]) + bias[f];
  if (RELU) v = fmaxf(v, 0.f);
  out[(size_t)node * 128 + f] = v;
}

// y[n,4] = A[n,128] @ W[128,4]
__global__ __launch_bounds__(256) void gemm_small4_k(const float* __restrict__ A,
                                                     const float* __restrict__ W,
                                                     float* __restrict__ Y, int n) {
  __shared__ float Ws[512];
  int tid = threadIdx.x;
  Ws[tid] = W[tid];
  Ws[tid + 256] = W[tid + 256];
  __syncthreads();
  int row = blockIdx.x * 256 + tid;
  if (row >= n) return;
  const float4* A4 = (const float4*)(A + (size_t)row * 128);
  float a0 = 0.f, a1 = 0.f, a2 = 0.f, a3 = 0.f;
#pragma unroll
  for (int k4 = 0; k4 < 32; ++k4) {
    float4 a = A4[k4];
    const float* w = &Ws[k4 * 16];
    a0 += a.x * w[0] + a.y * w[4] + a.z * w[8] + a.w * w[12];
    a1 += a.x * w[1] + a.y * w[5] + a.z * w[9] + a.w * w[13];
    a2 += a.x * w[2] + a.y * w[6] + a.z * w[10] + a.w * w[14];
    a3 += a.x * w[3] + a.y * w[7] + a.z * w[11] + a.w * w[15];
  }
  *(float4*)(Y + (size_t)row * 4) = make_float4(a0, a1, a2, a3);
}

// Gather-form propagate, 4 feats: 1 thread per node.
__global__ __launch_bounds__(256) void gather4_k(const int* __restrict__ col,
                                                 const int* __restrict__ rowptr,
                                                 const float* __restrict__ dinv,
                                                 const float* __restrict__ y,
                                                 const float* __restrict__ b2,
                                                 float* __restrict__ out, int n) {
  int node = blockIdx.x * 256 + threadIdx.x;
  if (node >= n) return;
  const int beg = rowptr[node], end = rowptr[node + 1];
  float ax = 0.f, ay = 0.f, az = 0.f, aw = 0.f;
  int p = beg;
  for (; p + 2 <= end; p += 2) {
    int s0 = col[p], s1 = col[p + 1];
    float d0 = dinv[s0], d1 = dinv[s1];
    float4 y0 = *(const float4*)(y + (size_t)s0 * 4);
    float4 y1 = *(const float4*)(y + (size_t)s1 * 4);
    ax += d0 * y0.x + d1 * y1.x;
    ay += d0 * y0.y + d1 * y1.y;
    az += d0 * y0.z + d1 * y1.z;
    aw += d0 * y0.w + d1 * y1.w;
  }
  for (; p < end; ++p) {
    int s = col[p];
    float ds = dinv[s];
    float4 yv = *(const float4*)(y + (size_t)s * 4);
    ax += ds * yv.x;
    ay += ds * yv.y;
    az += ds * yv.z;
    aw += ds * yv.w;
  }
  const float di = dinv[node];
  float4 yd = *(const float4*)(y + (size_t)node * 4);
  float4 o;
  o.x = di * (ax + di * yd.x) + b2[0];
  o.y = di * (ay + di * yd.y) + b2[1];
  o.z = di * (az + di * yd.z) + b2[2];
  o.w = di * (aw + di * yd.w) + b2[3];
  *(float4*)(out + (size_t)node * 4) = o;
}

extern "C" void kernel_launch(void* const* d_in, const int* in_sizes, int n_in,
                              void* d_out, int out_size, void* d_ws, size_t ws_size,
                              hipStream_t stream) {
  const float* clinical = (const float*)d_in[0];
  const float* mel = (const float*)d_in[1];
  const int* ei = (const int*)d_in[2];
  const float* W_mel = (const float*)d_in[3];
  const float* b_mel = (const float*)d_in[4];
  const float* W_cat = (const float*)d_in[5];
  const float* b_cat = (const float*)d_in[6];
  const float* W1 = (const float*)d_in[7];
  const float* b1 = (const float*)d_in[8];
  const float* W2 = (const float*)d_in[9];
  const float* b2 = (const float*)d_in[10];
  float* out = (float*)d_out;

  const int N = in_sizes[0] / 64;   // 100000
  const int E = in_sizes[2] / 2;    // 1600000
  const int B = (N + 255) / 256;    // scan blocks (391)

  // Workspace layout:
  //   bufA [N*128] f | bufB [N*128] f | dinv [N] f | ybuf [N*4] f |
  //   degi [N] i | rowptr [N+1] i | fill [N] i | partial [512] i |
  //   excl [512] i | col [E] i | Wt [128*1024] s |
  //   WcT_hi [128*192] s | WcT_lo [128*192] s | W1T_hi [128*128] s | W1T_lo s
  float* bufA = (float*)d_ws;
  float* bufB = bufA + (size_t)N * 128;
  float* dinv = bufB + (size_t)N * 128;
  float* ybuf = dinv + N;
  int* degi = (int*)(ybuf + (size_t)N * 4);
  int* rowptr = degi + N;
  int* fill = rowptr + (N + 1);
  int* partial = fill + N;
  int* excl = partial + 512;
  int* col = excl + 512;
  short* Wt = (short*)(col + E);
  short* WcT_hi = Wt + 128 * 1024;
  short* WcT_lo = WcT_hi + 128 * 192;
  short* W1T_hi = WcT_lo + 128 * 192;
  short* W1T_lo = W1T_hi + 128 * 128;

  const dim3 blk(256);

  // ---- CSR build + dinv + weight conversion
  zero_int_k<<<(N + 255) / 256, blk, 0, stream>>>(degi, N);
  count_deg_k<<<(E + 255) / 256, blk, 0, stream>>>(ei, degi, E);
  dinv_k<<<B, blk, 0, stream>>>(degi, dinv, N);
  scan_reduce_k<<<B, blk, 0, stream>>>(degi, partial, N);
  scan_partials_k<<<1, 512, 0, stream>>>(partial, excl, B, rowptr, N, E);
  scan_final_k<<<B, blk, 0, stream>>>(degi, excl, rowptr, N);
  zero_int_k<<<B, blk, 0, stream>>>(fill, N);
  fill_col_k<<<(E + 255) / 256, blk, 0, stream>>>(ei, rowptr, fill, col, E);
  convW_k<<<512, blk, 0, stream>>>(W_mel, Wt);
  convWsplit_k<<<128, 192, 0, stream>>>(W_cat, WcT_hi, WcT_lo, 192);
  convWsplit_k<<<128, 128, 0, stream>>>(W1, W1T_hi, W1T_lo, 128);

  // ---- dense pipeline
  mel_gemm_mfma_k<<<(N + 127) / 128, blk, 0, stream>>>(mel, Wt, b_mel, bufA, N);
  cat_w1_mfma_k<<<(N + 127) / 128, blk, 0, stream>>>(clinical, bufA, WcT_hi, WcT_lo,
                                                     W1T_hi, W1T_lo, b_cat, bufA, N);

  // ---- propagate 1 (fused finish+relu), bufA(h) -> bufB(x3)
  gather128_k<true><<<(N + 1) / 2, blk, 0, stream>>>(col, rowptr, dinv, bufA, b1, bufB, N);

  // ---- y = x3 @ W2 -> ybuf
  gemm_small4_k<<<(N + 255) / 256, blk, 0, stream>>>(bufB, W2, ybuf, N);

  // ---- propagate 2 (fused finish), ybuf -> out
  gather4_k<<<(N + 255) / 256, blk, 0, stream>>>(col, rowptr, dinv, ybuf, b2, out, N);
}